// Round 9
// baseline (404.644 us; speedup 1.0000x reference)
//
#include <hip/hip_runtime.h>

#define N_NODES  100000
#define N_EDGES  1600000
#define DIM      64
#define N_GRAPHS 128
#define OUT_DIM  10
#define SCAN_NB    196
#define SCAN_CHUNK 512      // 196*512 = 100352 >= N_NODES
#define RANGE_BITS 14
#define RANGE_SIZE 16384    // nodes per dst-range
#define N_RANGES   7        // 7*16384 = 114688 >= N_NODES
#define N_CHUNKS_F 64
#define CHUNK_EDGES_F (N_EDGES / N_CHUNKS_F)   // 25000
#define NODE_PAD   (N_RANGES * RANGE_SIZE)     // 114688

typedef unsigned int uint;
typedef unsigned short ushort;
typedef __attribute__((ext_vector_type(8))) short short8;   // 8 bf16 = 4 VGPRs
typedef __attribute__((ext_vector_type(4))) float f32x4;

__device__ __forceinline__ uint f2bf(float x) {   // fp32 -> bf16 bits (RNE)
    uint b = __float_as_uint(x);
    b += 0x7fffu + ((b >> 16) & 1u);
    return b >> 16;
}

// ---------------- CSR build v2: global per-node cursors, no base8 ----------------
// KEY: range-co-location (XCD = blockIdx%8 = r) makes per-node cursor atomics
// XCD-LOCAL — only range-r WGs touch nodes of range r, and they all run on XCD
// r. So fill can use atomicAdd on a global cur[] (copy of row_ptr) instead of
// per-chunk LDS bases: base8 (28.7MB traffic), counts8 slices (14.3MB), and
// fill's 64KB LDS all disappear. histo only needs per-node TOTALS -> LDS
// histogram dumped via atomicAdd into one counts[] array. fill: no LDS ->
// 512 blocks = 2 blocks/CU = 32 waves/CU (was 16).

__global__ __launch_bounds__(1024) void histo_kernel(const int* __restrict__ dst,
                                                     int* __restrict__ counts) {
    __shared__ int lds[RANGE_SIZE];
    const int r = blockIdx.x & 7;        // XCD id == r -> counts atomics XCD-local
    const int c = blockIdx.x >> 3;
    if (r >= N_RANGES) return;
    for (int j = threadIdx.x; j < RANGE_SIZE; j += 1024) lds[j] = 0;
    __syncthreads();
    const int beg = c * CHUNK_EDGES_F, end = beg + CHUNK_EDGES_F;
    for (int i0 = beg + threadIdx.x; i0 < end; i0 += 1024 * 8) {
        int d[8];                       // 8 coalesced loads in flight per thread
#pragma unroll
        for (int k = 0; k < 8; ++k) {
            const int i = i0 + k * 1024;
            d[k] = (i < end) ? dst[i] : -1;
        }
#pragma unroll
        for (int k = 0; k < 8; ++k)
            if ((d[k] >> RANGE_BITS) == r) atomicAdd(&lds[d[k] & (RANGE_SIZE - 1)], 1);
    }
    __syncthreads();
    int* cnt = counts + r * RANGE_SIZE;
    for (int j = threadIdx.x; j < RANGE_SIZE; j += 1024) {
        int v = lds[j];
        if (v) atomicAdd(&cnt[j], v);    // ~20% nonzero; XCD-local L2 atomic
    }
}

__global__ void scanA_kernel(const int* __restrict__ counts, int* __restrict__ blockSums, int n) {
    __shared__ int red[256];
    const int b = blockIdx.x, t = threadIdx.x;
    int s = 0;
#pragma unroll
    for (int k = 0; k < 2; ++k) {
        const int node = b * SCAN_CHUNK + t * 2 + k;
        if (node < n) s += counts[node];
    }
    red[t] = s;
    __syncthreads();
    for (int off = 128; off > 0; off >>= 1) {
        if (t < off) red[t] += red[t + off];
        __syncthreads();
    }
    if (t == 0) blockSums[b] = red[0];
}

__global__ void scanB_kernel(const int* __restrict__ blockSums, int* __restrict__ blockOffs,
                             int* __restrict__ row_ptr) {
    __shared__ int sc[256];
    const int t = threadIdx.x;
    const int v = (t < SCAN_NB) ? blockSums[t] : 0;
    sc[t] = v;
    __syncthreads();
    for (int off = 1; off < 256; off <<= 1) {
        int u = (t >= off) ? sc[t - off] : 0;
        __syncthreads();
        sc[t] += u;
        __syncthreads();
    }
    if (t < SCAN_NB) blockOffs[t] = sc[t] - v;   // exclusive block offset
    if (t == 255) row_ptr[N_NODES] = sc[255];    // total == N_EDGES
}

// row_ptr (stable) + cur (mutable fill cursors), both = exclusive prefix
__global__ void scanC_kernel(const int* __restrict__ counts, const int* __restrict__ blockOffs,
                             int* __restrict__ row_ptr, int* __restrict__ cur, int n) {
    __shared__ int sc[256];
    const int b = blockIdx.x, t = threadIdx.x;
    const int node0 = b * SCAN_CHUNK + t * 2;
    const int c0 = (node0 < n) ? counts[node0] : 0;
    const int c1 = (node0 + 1 < n) ? counts[node0 + 1] : 0;
    const int s = c0 + c1;
    sc[t] = s;
    __syncthreads();
    for (int off = 1; off < 256; off <<= 1) {
        int u = (t >= off) ? sc[t - off] : 0;
        __syncthreads();
        sc[t] += u;
        __syncthreads();
    }
    const int pre = blockOffs[b] + sc[t] - s;    // exclusive prefix for node0
    if (node0 < n)     { row_ptr[node0] = pre;          cur[node0] = pre; }
    if (node0 + 1 < n) { row_ptr[node0 + 1] = pre + c0; cur[node0 + 1] = pre + c0; }
}

// fill v2: no LDS, global XCD-local cursors. col_idx writes stay range-local
// (R1's write-side co-location preserved: range r's span lives in XCD r's L2).
__global__ __launch_bounds__(1024) void fill_kernel(const int* __restrict__ src,
                                                    const int* __restrict__ dst,
                                                    int* __restrict__ cur,
                                                    int* __restrict__ col_idx) {
    const int r = blockIdx.x & 7;        // XCD id == r
    const int c = blockIdx.x >> 3;
    if (r >= N_RANGES) return;
    const int beg = c * CHUNK_EDGES_F, end = beg + CHUNK_EDGES_F;
    for (int i0 = beg + threadIdx.x; i0 < end; i0 += 1024 * 8) {
        int d[8], s[8];                  // 16 coalesced loads in flight per thread
#pragma unroll
        for (int k = 0; k < 8; ++k) {
            const int i = i0 + k * 1024;
            d[k] = (i < end) ? dst[i] : -1;
            s[k] = (i < end) ? src[i] : 0;
        }
#pragma unroll
        for (int k = 0; k < 8; ++k) {
            if ((d[k] >> RANGE_BITS) == r) {
                int pos = atomicAdd(&cur[d[k]], 1);   // XCD-local L2 atomic
                col_idx[pos] = s[k];                  // XCD-local, merged write-back
            }
        }
    }
}

// ---------------- x (fp32) -> bf16 rows ----------------

__global__ void cvt_kernel(const float* __restrict__ x, ushort* __restrict__ xb, int n4) {
    int idx = blockIdx.x * blockDim.x + threadIdx.x;
    if (idx >= n4) return;
    float4 v = ((const float4*)x)[idx];
    uint2 o;
    o.x = f2bf(v.x) | (f2bf(v.y) << 16);
    o.y = f2bf(v.z) | (f2bf(v.w) << 16);
    ((uint2*)xb)[idx] = o;
}

// ---------------- Weight repack: MFMA fragment layouts, once per launch ----------

__global__ void repack_kernel(const float* __restrict__ W1, const float* __restrict__ W2,
                              uint4* __restrict__ Wp) {
    const int wave = (blockIdx.x * blockDim.x + threadIdx.x) >> 6;
    if (wave >= 10) return;
    const int layer = wave >> 1;
    const float* W = (wave & 1) ? (W2 + layer * 4096) : (W1 + layer * 4096);
    const int lane = threadIdx.x & 63;
    const int n15 = lane & 15, quad = lane >> 4;
#pragma unroll
    for (int f = 0; f < 8; ++f) {
        const int outer = f >> 1, h = f & 1;
        uint p[4];
#pragma unroll
        for (int pj = 0; pj < 4; ++pj) {
            const int k0 = h * 32 + quad * 8 + 2 * pj;
            uint lo = f2bf(W[k0 * 64 + outer * 16 + n15]);
            uint hi = f2bf(W[(k0 + 1) * 64 + outer * 16 + n15]);
            p[pj] = lo | (hi << 16);
        }
        Wp[(wave * 8 + f) * 64 + lane] = make_uint4(p[0], p[1], p[2], p[3]);
    }
}

// ---------------- Fused GIN layer (R7 config: 16-node tiles, verified 345us) ----
// R8 post-mortem: 8-node tiles doubled per-node MLP overhead (VALUBusy 29->44%,
// LDS conflicts 2x) and regressed 36->44.5us despite higher occupancy. The
// 16-node tile is the balance point. R7 structure restored verbatim:
// wave-independent (no barriers), masked 8-wide batches with zero-row pad,
// software-pipelined col_idx, W-frags hoisted above the threadfences.

__device__ __forceinline__ void add_unpack(float acc[8], uint4 v) {
    acc[0] += __uint_as_float(v.x << 16);
    acc[1] += __uint_as_float(v.x & 0xffff0000u);
    acc[2] += __uint_as_float(v.y << 16);
    acc[3] += __uint_as_float(v.y & 0xffff0000u);
    acc[4] += __uint_as_float(v.z << 16);
    acc[5] += __uint_as_float(v.z & 0xffff0000u);
    acc[6] += __uint_as_float(v.w << 16);
    acc[7] += __uint_as_float(v.w & 0xffff0000u);
}

__global__ __launch_bounds__(256) void layer_kernel(
    const ushort* __restrict__ hbp, ushort* __restrict__ hbn,
    const int* __restrict__ row_ptr, const int* __restrict__ col_idx,
    const uint4* __restrict__ Wp,   // layer frags: [0..7]=W1^T, [8..15]=W2
    const float* __restrict__ b1, const float* __restrict__ gamma,
    const float* __restrict__ beta, const float* __restrict__ rmean,
    const float* __restrict__ rvar, const float* __restrict__ b2, int ntiles)
{
    __shared__ __align__(16) ushort Ua[4][16][72];   // agg out / GEMM1 in (per-wave slice)
    __shared__ __align__(16) ushort Ub[4][16][72];   // GEMM1 out / GEMM2 in (per-wave slice)
    const uint4* __restrict__ hb4 = (const uint4*)hbp;   // row = 8 uint4
    const int lane = threadIdx.x & 63;
    const int wid  = threadIdx.x >> 6;
    const int n15  = lane & 15, quad = lane >> 4;
    const int g = lane >> 3;     // node slot within round
    const int q = lane & 7;      // 16B chunk within row
    const short8* Wp8 = (const short8*)Wp;

    const int tile = blockIdx.x * 4 + wid;   // one 16-node tile per wave
    if (tile >= ntiles) return;              // whole-wave exit; no barriers anywhere
    const int nb = tile * 16;

    // ---- phase 1: aggregate 16 nodes -> Ua[wid] (bf16, node-row layout) ----
    for (int ro = 0; ro < 2; ++ro) {
        const int i = nb + ro * 8 + g;
        const int rp0 = row_ptr[i];
        const int rp1 = row_ptr[i + 1];
        float acc[8];
        {   // self term (eps = 0)
            uint4 v = hb4[(size_t)i * 8 + q];
            acc[0] = __uint_as_float(v.x << 16);
            acc[1] = __uint_as_float(v.x & 0xffff0000u);
            acc[2] = __uint_as_float(v.y << 16);
            acc[3] = __uint_as_float(v.y & 0xffff0000u);
            acc[4] = __uint_as_float(v.z << 16);
            acc[5] = __uint_as_float(v.z & 0xffff0000u);
            acc[6] = __uint_as_float(v.w << 16);
            acc[7] = __uint_as_float(v.w & 0xffff0000u);
        }
        const int nbat = (rp1 - rp0 + 7) >> 3;   // uniform full batches, masked tail
        int ixn[8];   // pipelined index buffer (batch b+1 loads during batch b)
#pragma unroll
        for (int k = 0; k < 8; ++k)
            ixn[k] = col_idx[max(min(rp0 + k, rp1 - 1), 0)];   // max: deg-0 safety
        for (int b = 0; b < nbat; ++b) {
            const int e0 = rp0 + b * 8;
            int ix[8];
#pragma unroll
            for (int k = 0; k < 8; ++k)
                ix[k] = (e0 + k < rp1) ? ixn[k] : N_NODES;     // pad -> zero row
#pragma unroll
            for (int k = 0; k < 8; ++k)                        // prefetch batch b+1
                ixn[k] = col_idx[min(e0 + 8 + k, rp1 - 1)];    // rp1>=1 here: safe
            uint4 v[8];
#pragma unroll
            for (int k = 0; k < 8; ++k) v[k] = hb4[(size_t)ix[k] * 8 + q];
#pragma unroll
            for (int k = 0; k < 8; ++k) add_unpack(acc, v[k]);
        }
        uint2 o0, o1;   // dims q*8 .. q*8+7 of node-row ro*8+g
        o0.x = f2bf(acc[0]) | (f2bf(acc[1]) << 16);
        o0.y = f2bf(acc[2]) | (f2bf(acc[3]) << 16);
        o1.x = f2bf(acc[4]) | (f2bf(acc[5]) << 16);
        o1.y = f2bf(acc[6]) | (f2bf(acc[7]) << 16);
        *(uint2*)&Ua[wid][ro * 8 + g][q * 8]     = o0;
        *(uint2*)&Ua[wid][ro * 8 + g][q * 8 + 4] = o1;
    }
    // W1^T frags: independent of LDS -> issue BEFORE the fence, overlap gather tail
    short8 wf1[8];
#pragma unroll
    for (int f = 0; f < 8; ++f) wf1[f] = Wp8[f * 64 + lane];
    __threadfence_block();   // same-wave LDS visibility (lgkmcnt), no inter-wave wait

    // ---- phase 2: GEMM1 + BN + ReLU -> Ub[wid] ----
    short8 t0 = *(const short8*)&Ua[wid][n15][quad * 8];        // k 0..31
    short8 t1 = *(const short8*)&Ua[wid][n15][32 + quad * 8];   // k 32..63
    {
        f32x4 c1[4];
#pragma unroll
        for (int mt = 0; mt < 4; ++mt) {
            c1[mt] = (f32x4){0.f, 0.f, 0.f, 0.f};
            c1[mt] = __builtin_amdgcn_mfma_f32_16x16x32_bf16(wf1[mt * 2 + 0], t0, c1[mt], 0, 0, 0);
            c1[mt] = __builtin_amdgcn_mfma_f32_16x16x32_bf16(wf1[mt * 2 + 1], t1, c1[mt], 0, 0, 0);
        }
        // BN constants computed here (not live during gather)
#pragma unroll
        for (int mt = 0; mt < 4; ++mt) {
            const int j0 = mt * 16 + quad * 4;
            f32x4 sc, sh;
#pragma unroll
            for (int r = 0; r < 4; ++r) {
                float s = gamma[j0 + r] * rsqrtf(rvar[j0 + r] + 1e-5f);
                sc[r] = s;
                sh[r] = (b1[j0 + r] - rmean[j0 + r]) * s + beta[j0 + r];
            }
            float u0 = fmaxf(c1[mt][0] * sc[0] + sh[0], 0.f);
            float u1 = fmaxf(c1[mt][1] * sc[1] + sh[1], 0.f);
            float u2 = fmaxf(c1[mt][2] * sc[2] + sh[2], 0.f);
            float u3 = fmaxf(c1[mt][3] * sc[3] + sh[3], 0.f);
            uint2 pk;
            pk.x = f2bf(u0) | (f2bf(u1) << 16);
            pk.y = f2bf(u2) | (f2bf(u3) << 16);
            *(uint2*)&Ub[wid][n15][mt * 16 + quad * 4] = pk;
        }
    }
    // W2 frags: issue before the fence, overlap phase-2 tail
    short8 wf2[8];
#pragma unroll
    for (int f = 0; f < 8; ++f) wf2[f] = Wp8[(8 + f) * 64 + lane];
    __threadfence_block();   // same-wave LDS visibility

    // ---- phase 3: GEMM2 + ReLU -> hb_next ----
    {
        short8 u0 = *(const short8*)&Ub[wid][n15][quad * 8];
        short8 u1 = *(const short8*)&Ub[wid][n15][32 + quad * 8];
        f32x4 c2[4];
#pragma unroll
        for (int tc = 0; tc < 4; ++tc) {
            c2[tc] = (f32x4){0.f, 0.f, 0.f, 0.f};
            c2[tc] = __builtin_amdgcn_mfma_f32_16x16x32_bf16(u0, wf2[tc * 2 + 0], c2[tc], 0, 0, 0);
            c2[tc] = __builtin_amdgcn_mfma_f32_16x16x32_bf16(u1, wf2[tc * 2 + 1], c2[tc], 0, 0, 0);
        }
#pragma unroll
        for (int tc = 0; tc < 4; ++tc) {
            const float bb2 = b2[tc * 16 + n15];
#pragma unroll
            for (int r = 0; r < 4; ++r) {
                float v = fmaxf(c2[tc][r] + bb2, 0.f);
                hbn[(size_t)(nb + quad * 4 + r) * 64 + tc * 16 + n15] = (ushort)f2bf(v);
            }
        }
    }
}

// ---------------- global_add_pool (batch sorted -> run-length + atomics) --------

__global__ void pool_kernel(const ushort* __restrict__ hb, const int* __restrict__ batch,
                            float* __restrict__ pooled, int n) {
    const int lane = threadIdx.x & 63;
    const int wid  = threadIdx.x >> 6;
    const int wave = blockIdx.x * 4 + wid;
    const int nwaves = gridDim.x * 4;
    const int per = (n + nwaves - 1) / nwaves;
    const int a = wave * per;
    const int b = min(a + per, n);
    if (a >= b) return;
    int cur = batch[a];
    float sum = 0.0f;
    for (int i = a; i < b; ++i) {
        int g = batch[i];
        if (g != cur) {
            atomicAdd(&pooled[cur * DIM + lane], sum);
            sum = 0.0f;
            cur = g;
        }
        sum += __uint_as_float(((uint)hb[(size_t)i * DIM + lane]) << 16);
    }
    atomicAdd(&pooled[cur * DIM + lane], sum);
}

// ---------------- head: relu(pooled@lin1+b1) @ lin2 + b2 ----------------

__global__ void head_kernel(const float* __restrict__ pooled,
                            const float* __restrict__ w1, const float* __restrict__ b1,
                            const float* __restrict__ w2, const float* __restrict__ b2,
                            float* __restrict__ out) {
    const int g = blockIdx.x;
    const int lane = threadIdx.x;  // 64 threads = 1 wave
    __shared__ float pl[DIM];
    __shared__ float y1l[DIM];
    pl[lane] = pooled[g * DIM + lane];
    __syncthreads();
    float y = b1[lane];
#pragma unroll
    for (int d = 0; d < DIM; ++d) y += pl[d] * w1[d * DIM + lane];
    y1l[lane] = fmaxf(y, 0.0f);
    __syncthreads();
    if (lane < OUT_DIM) {
        float y2 = b2[lane];
#pragma unroll
        for (int d = 0; d < DIM; ++d) y2 += y1l[d] * w2[d * OUT_DIM + lane];
        out[g * OUT_DIM + lane] = y2;
    }
}

// ---------------- launch ----------------

extern "C" void kernel_launch(void* const* d_in, const int* in_sizes, int n_in,
                              void* d_out, int out_size, void* d_ws, size_t ws_size,
                              hipStream_t stream) {
    const float* x     = (const float*)d_in[0];
    const int*   eidx  = (const int*)  d_in[1];   // [2, N_EDGES]: src row then dst row
    const int*   batch = (const int*)  d_in[2];
    const float* W1    = (const float*)d_in[3];
    const float* b1    = (const float*)d_in[4];
    const float* gamma = (const float*)d_in[5];
    const float* beta  = (const float*)d_in[6];
    const float* rmean = (const float*)d_in[7];
    const float* rvar  = (const float*)d_in[8];
    const float* W2    = (const float*)d_in[9];
    const float* b2    = (const float*)d_in[10];
    const float* l1w   = (const float*)d_in[11];
    const float* l1b   = (const float*)d_in[12];
    const float* l2w   = (const float*)d_in[13];
    const float* l2b   = (const float*)d_in[14];
    float* out = (float*)d_out;

    // workspace layout (int-element offsets; 16B alignment preserved)
    const size_t ROWS = (size_t)N_NODES + 1;      // +1 zero row for masked gather pad
    int* counts    = (int*)d_ws;                  // NODE_PAD (114688; tail bins unused)
    int* row_ptr   = counts    + NODE_PAD;        // 100352
    int* cur       = row_ptr   + 100352;          // 100352 (mutable fill cursors)
    int* blockSums = cur       + 100352;          // 256
    int* blockOffs = blockSums + 256;             // 256
    int* col_idx   = blockOffs + 256;             // 1600000
    uint4* Wp      = (uint4*)(col_idx + 1600000); // 5120 uint4 = 80KB
    ushort* tb     = (ushort*)(Wp + 5120);        // (100000+1)*64 bf16  [ping]
    ushort* hb     = tb + ROWS * DIM;             // (100000+1)*64 bf16  [pong]
    float* pooled  = (float*)(hb + ROWS * DIM);   // 128*64 fp32

    const int* srcp = eidx;
    const int* dstp = eidx + N_EDGES;

    hipMemsetAsync(counts, 0, NODE_PAD * sizeof(int), stream);
    hipMemsetAsync(pooled, 0, N_GRAPHS * DIM * sizeof(float), stream);
    // zero pad row (index N_NODES) in BOTH ping-pong buffers; never written after
    hipMemsetAsync(tb + (size_t)N_NODES * DIM, 0, DIM * sizeof(ushort), stream);
    hipMemsetAsync(hb + (size_t)N_NODES * DIM, 0, DIM * sizeof(ushort), stream);

    cvt_kernel<<<(N_NODES * DIM / 4 + 255) / 256, 256, 0, stream>>>(x, hb, N_NODES * DIM / 4);
    repack_kernel<<<1, 640, 0, stream>>>(W1, W2, Wp);
    histo_kernel<<<N_CHUNKS_F * 8, 1024, 0, stream>>>(dstp, counts);
    scanA_kernel<<<SCAN_NB, 256, 0, stream>>>(counts, blockSums, N_NODES);
    scanB_kernel<<<1, 256, 0, stream>>>(blockSums, blockOffs, row_ptr);
    scanC_kernel<<<SCAN_NB, 256, 0, stream>>>(counts, blockOffs, row_ptr, cur, N_NODES);
    fill_kernel<<<N_CHUNKS_F * 8, 1024, 0, stream>>>(srcp, dstp, cur, col_idx);

    const int ntiles = N_NODES / 16;             // 6250 16-node tiles (R7 config)
    const int layer_blocks = (ntiles + 3) / 4;   // 1563: one tile per wave
    ushort* curb = hb;
    ushort* nxtb = tb;
    for (int l = 0; l < 5; ++l) {
        layer_kernel<<<layer_blocks, 256, 0, stream>>>(
            curb, nxtb, row_ptr, col_idx, Wp + (size_t)l * 2 * 8 * 64,
            b1 + (size_t)l * DIM, gamma + (size_t)l * DIM, beta + (size_t)l * DIM,
            rmean + (size_t)l * DIM, rvar + (size_t)l * DIM, b2 + (size_t)l * DIM, ntiles);
        ushort* t = curb; curb = nxtb; nxtb = t;
    }
    pool_kernel<<<2048, 256, 0, stream>>>(curb, batch, pooled, N_NODES);
    head_kernel<<<N_GRAPHS, 64, 0, stream>>>(pooled, l1w, l1b, l2w, l2b, out);
}

// Round 10
// 368.850 us; speedup vs baseline: 1.0970x; 1.0970x over previous
//
#include <hip/hip_runtime.h>

#define N_NODES  100000
#define N_EDGES  1600000
#define DIM      64
#define N_GRAPHS 128
#define OUT_DIM  10
#define SCAN_NB    196
#define SCAN_CHUNK 512      // 196*512 = 100352 >= N_NODES
#define RANGE_BITS 14
#define RANGE_SIZE 16384    // nodes per dst-range
#define N_RANGES   7        // 7*16384 = 114688 >= N_NODES
#define N_CHUNKS   64       // R10: 32->64 -> 512 blocks = 2 blocks/CU (64KB LDS) = 32 waves/CU
#define CHUNK_EDGES (N_EDGES / N_CHUNKS)   // 25000
#define NODE_PAD   (N_RANGES * RANGE_SIZE) // 114688

typedef unsigned int uint;
typedef unsigned short ushort;
typedef __attribute__((ext_vector_type(8))) short short8;   // 8 bf16 = 4 VGPRs
typedef __attribute__((ext_vector_type(4))) float f32x4;

__device__ __forceinline__ uint f2bf(float x) {   // fp32 -> bf16 bits (RNE)
    uint b = __float_as_uint(x);
    b += 0x7fffu + ((b >> 16) & 1u);
    return b >> 16;
}

// ---------------- CSR build (R7 structure, 64 chunks) ----------------
// R9 post-mortem: global per-node cursor atomics thrashed dirty lines (WRITE
// 6.5->78MB, fill 42->74us). Per-chunk LDS cursor staging (base8) is load-
// bearing — restored. Total edge-read volume is INVARIANT in chunk count
// (sum over blocks = N_RANGES x edge list), so 64 chunks only adds blocks:
// 448 active on 256 CUs = ~2/CU -> 32 waves/CU (was <1 block/CU, 16 waves).
// histo: chunk-co-located (XCD = blockIdx%8 = c%8) -> chunk read once per XCD.

__global__ __launch_bounds__(1024) void histo_kernel(const int* __restrict__ dst,
                                                     int* __restrict__ counts8) {
    __shared__ int lds[RANGE_SIZE];
    const int c = blockIdx.x & (N_CHUNKS - 1);
    const int r = blockIdx.x / N_CHUNKS;
    if (r >= N_RANGES) return;
    for (int j = threadIdx.x; j < RANGE_SIZE; j += 1024) lds[j] = 0;
    __syncthreads();
    const int beg = c * CHUNK_EDGES, end = beg + CHUNK_EDGES;
    for (int i0 = beg + threadIdx.x; i0 < end; i0 += 1024 * 8) {
        int d[8];                       // 8 coalesced loads in flight per thread
#pragma unroll
        for (int k = 0; k < 8; ++k) {
            const int i = i0 + k * 1024;
            d[k] = (i < end) ? dst[i] : -1;
        }
#pragma unroll
        for (int k = 0; k < 8; ++k)
            if ((d[k] >> RANGE_BITS) == r) atomicAdd(&lds[d[k] & (RANGE_SIZE - 1)], 1);
    }
    __syncthreads();
    int* outp = counts8 + (c * N_RANGES + r) * RANGE_SIZE;   // contiguous 64KB dump
    for (int j = threadIdx.x; j < RANGE_SIZE; j += 1024) outp[j] = lds[j];
}

__global__ void scanA_kernel(const int* __restrict__ counts8, int* __restrict__ blockSums, int n) {
    __shared__ int red[256];
    const int b = blockIdx.x, t = threadIdx.x;
    int s = 0;
#pragma unroll
    for (int k = 0; k < 2; ++k) {
        const int node = b * SCAN_CHUNK + t * 2 + k;
        if (node < n) {
            const int r = node >> RANGE_BITS, jj = node & (RANGE_SIZE - 1);
            for (int c = 0; c < N_CHUNKS; ++c)
                s += counts8[(c * N_RANGES + r) * RANGE_SIZE + jj];
        }
    }
    red[t] = s;
    __syncthreads();
    for (int off = 128; off > 0; off >>= 1) {
        if (t < off) red[t] += red[t + off];
        __syncthreads();
    }
    if (t == 0) blockSums[b] = red[0];
}

__global__ void scanB_kernel(const int* __restrict__ blockSums, int* __restrict__ blockOffs,
                             int* __restrict__ row_ptr) {
    __shared__ int sc[256];
    const int t = threadIdx.x;
    const int v = (t < SCAN_NB) ? blockSums[t] : 0;
    sc[t] = v;
    __syncthreads();
    for (int off = 1; off < 256; off <<= 1) {
        int u = (t >= off) ? sc[t - off] : 0;
        __syncthreads();
        sc[t] += u;
        __syncthreads();
    }
    if (t < SCAN_NB) blockOffs[t] = sc[t] - v;   // exclusive block offset
    if (t == 255) row_ptr[N_NODES] = sc[255];    // total == N_EDGES
}

// row_ptr + per-chunk slot bases base8[c][node]. With 64 chunks the per-chunk
// counts no longer fit in registers (2x64 ints would spill) -> sum-then-rewalk:
// second pass re-reads counts8 (L2/L3-hot) while accumulating the running base.
__global__ void scanC_kernel(const int* __restrict__ counts8, const int* __restrict__ blockOffs,
                             int* __restrict__ row_ptr, int* __restrict__ base8, int n) {
    __shared__ int sc[256];
    const int b = blockIdx.x, t = threadIdx.x;
    const int node0 = b * SCAN_CHUNK + t * 2;
    int r0 = 0, jj0 = 0, r1 = 0, jj1 = 0;
    int tot0 = 0, tot1 = 0;
    if (node0 < n) {
        r0 = node0 >> RANGE_BITS; jj0 = node0 & (RANGE_SIZE - 1);
        for (int c = 0; c < N_CHUNKS; ++c)
            tot0 += counts8[(c * N_RANGES + r0) * RANGE_SIZE + jj0];
    }
    if (node0 + 1 < n) {
        r1 = (node0 + 1) >> RANGE_BITS; jj1 = (node0 + 1) & (RANGE_SIZE - 1);
        for (int c = 0; c < N_CHUNKS; ++c)
            tot1 += counts8[(c * N_RANGES + r1) * RANGE_SIZE + jj1];
    }
    const int s = tot0 + tot1;
    sc[t] = s;
    __syncthreads();
    for (int off = 1; off < 256; off <<= 1) {
        int u = (t >= off) ? sc[t - off] : 0;
        __syncthreads();
        sc[t] += u;
        __syncthreads();
    }
    const int pre = blockOffs[b] + sc[t] - s;    // exclusive prefix for node0
    if (node0 < n) {
        row_ptr[node0] = pre;
        int run = pre;
        for (int c = 0; c < N_CHUNKS; ++c) {
            base8[c * NODE_PAD + node0] = run;
            run += counts8[(c * N_RANGES + r0) * RANGE_SIZE + jj0];
        }
    }
    if (node0 + 1 < n) {
        const int pre1 = pre + tot0;
        row_ptr[node0 + 1] = pre1;
        int run = pre1;
        for (int c = 0; c < N_CHUNKS; ++c) {
            base8[c * NODE_PAD + node0 + 1] = run;
            run += counts8[(c * N_RANGES + r1) * RANGE_SIZE + jj1];
        }
    }
}

// fill: RANGE-co-located (XCD = blockIdx%8 = r): range r's ~914KB col_idx span
// accumulates in ONE L2 -> near-full-line write-backs (R1: WRITE 59.8->6.5MB).
// dst/src are PLAIN cached loads; base8 stays NT (read exactly once, one XCD).

__global__ __launch_bounds__(1024) void fill_kernel(const int* __restrict__ src,
                                                    const int* __restrict__ dst,
                                                    const int* __restrict__ base8,
                                                    int* __restrict__ col_idx) {
    __shared__ int lds[RANGE_SIZE];
    const int r = blockIdx.x & 7;        // XCD id == r  -> write-side co-location
    const int c = blockIdx.x >> 3;
    if (r >= N_RANGES) return;
    const int* bp = base8 + c * NODE_PAD + r * RANGE_SIZE;
    for (int j = threadIdx.x; j < RANGE_SIZE; j += 1024)
        lds[j] = __builtin_nontemporal_load(&bp[j]);
    __syncthreads();
    const int beg = c * CHUNK_EDGES, end = beg + CHUNK_EDGES;
    for (int i0 = beg + threadIdx.x; i0 < end; i0 += 1024 * 8) {
        int d[8], s[8];                  // 16 coalesced loads in flight per thread
#pragma unroll
        for (int k = 0; k < 8; ++k) {
            const int i = i0 + k * 1024;
            d[k] = (i < end) ? dst[i] : -1;
            s[k] = (i < end) ? src[i] : 0;
        }
#pragma unroll
        for (int k = 0; k < 8; ++k) {
            if ((d[k] >> RANGE_BITS) == r) {
                int pos = atomicAdd(&lds[d[k] & (RANGE_SIZE - 1)], 1);
                col_idx[pos] = s[k];     // cached: L2-absorbed, merged write-back
            }
        }
    }
}

// ---------------- x (fp32) -> bf16 rows ----------------

__global__ void cvt_kernel(const float* __restrict__ x, ushort* __restrict__ xb, int n4) {
    int idx = blockIdx.x * blockDim.x + threadIdx.x;
    if (idx >= n4) return;
    float4 v = ((const float4*)x)[idx];
    uint2 o;
    o.x = f2bf(v.x) | (f2bf(v.y) << 16);
    o.y = f2bf(v.z) | (f2bf(v.w) << 16);
    ((uint2*)xb)[idx] = o;
}

// ---------------- Weight repack: MFMA fragment layouts, once per launch ----------

__global__ void repack_kernel(const float* __restrict__ W1, const float* __restrict__ W2,
                              uint4* __restrict__ Wp) {
    const int wave = (blockIdx.x * blockDim.x + threadIdx.x) >> 6;
    if (wave >= 10) return;
    const int layer = wave >> 1;
    const float* W = (wave & 1) ? (W2 + layer * 4096) : (W1 + layer * 4096);
    const int lane = threadIdx.x & 63;
    const int n15 = lane & 15, quad = lane >> 4;
#pragma unroll
    for (int f = 0; f < 8; ++f) {
        const int outer = f >> 1, h = f & 1;
        uint p[4];
#pragma unroll
        for (int pj = 0; pj < 4; ++pj) {
            const int k0 = h * 32 + quad * 8 + 2 * pj;
            uint lo = f2bf(W[k0 * 64 + outer * 16 + n15]);
            uint hi = f2bf(W[(k0 + 1) * 64 + outer * 16 + n15]);
            p[pj] = lo | (hi << 16);
        }
        Wp[(wave * 8 + f) * 64 + lane] = make_uint4(p[0], p[1], p[2], p[3]);
    }
}

// ---------------- Fused GIN layer (R7 config: 16-node tiles, verified 345us) ----
// Wave-independent (no barriers, per-wave LDS slices + threadfence), masked
// 8-wide batches with zero-row pad, software-pipelined col_idx, W-frags hoisted
// above the threadfences. R8 proved 8-node tiles regress (2x MLP overhead).

__device__ __forceinline__ void add_unpack(float acc[8], uint4 v) {
    acc[0] += __uint_as_float(v.x << 16);
    acc[1] += __uint_as_float(v.x & 0xffff0000u);
    acc[2] += __uint_as_float(v.y << 16);
    acc[3] += __uint_as_float(v.y & 0xffff0000u);
    acc[4] += __uint_as_float(v.z << 16);
    acc[5] += __uint_as_float(v.z & 0xffff0000u);
    acc[6] += __uint_as_float(v.w << 16);
    acc[7] += __uint_as_float(v.w & 0xffff0000u);
}

__global__ __launch_bounds__(256) void layer_kernel(
    const ushort* __restrict__ hbp, ushort* __restrict__ hbn,
    const int* __restrict__ row_ptr, const int* __restrict__ col_idx,
    const uint4* __restrict__ Wp,   // layer frags: [0..7]=W1^T, [8..15]=W2
    const float* __restrict__ b1, const float* __restrict__ gamma,
    const float* __restrict__ beta, const float* __restrict__ rmean,
    const float* __restrict__ rvar, const float* __restrict__ b2, int ntiles)
{
    __shared__ __align__(16) ushort Ua[4][16][72];   // agg out / GEMM1 in (per-wave slice)
    __shared__ __align__(16) ushort Ub[4][16][72];   // GEMM1 out / GEMM2 in (per-wave slice)
    const uint4* __restrict__ hb4 = (const uint4*)hbp;   // row = 8 uint4
    const int lane = threadIdx.x & 63;
    const int wid  = threadIdx.x >> 6;
    const int n15  = lane & 15, quad = lane >> 4;
    const int g = lane >> 3;     // node slot within round
    const int q = lane & 7;      // 16B chunk within row
    const short8* Wp8 = (const short8*)Wp;

    const int tile = blockIdx.x * 4 + wid;   // one 16-node tile per wave
    if (tile >= ntiles) return;              // whole-wave exit; no barriers anywhere
    const int nb = tile * 16;

    // ---- phase 1: aggregate 16 nodes -> Ua[wid] (bf16, node-row layout) ----
    for (int ro = 0; ro < 2; ++ro) {
        const int i = nb + ro * 8 + g;
        const int rp0 = row_ptr[i];
        const int rp1 = row_ptr[i + 1];
        float acc[8];
        {   // self term (eps = 0)
            uint4 v = hb4[(size_t)i * 8 + q];
            acc[0] = __uint_as_float(v.x << 16);
            acc[1] = __uint_as_float(v.x & 0xffff0000u);
            acc[2] = __uint_as_float(v.y << 16);
            acc[3] = __uint_as_float(v.y & 0xffff0000u);
            acc[4] = __uint_as_float(v.z << 16);
            acc[5] = __uint_as_float(v.z & 0xffff0000u);
            acc[6] = __uint_as_float(v.w << 16);
            acc[7] = __uint_as_float(v.w & 0xffff0000u);
        }
        const int nbat = (rp1 - rp0 + 7) >> 3;   // uniform full batches, masked tail
        int ixn[8];   // pipelined index buffer (batch b+1 loads during batch b)
#pragma unroll
        for (int k = 0; k < 8; ++k)
            ixn[k] = col_idx[max(min(rp0 + k, rp1 - 1), 0)];   // max: deg-0 safety
        for (int b = 0; b < nbat; ++b) {
            const int e0 = rp0 + b * 8;
            int ix[8];
#pragma unroll
            for (int k = 0; k < 8; ++k)
                ix[k] = (e0 + k < rp1) ? ixn[k] : N_NODES;     // pad -> zero row
#pragma unroll
            for (int k = 0; k < 8; ++k)                        // prefetch batch b+1
                ixn[k] = col_idx[min(e0 + 8 + k, rp1 - 1)];    // rp1>=1 here: safe
            uint4 v[8];
#pragma unroll
            for (int k = 0; k < 8; ++k) v[k] = hb4[(size_t)ix[k] * 8 + q];
#pragma unroll
            for (int k = 0; k < 8; ++k) add_unpack(acc, v[k]);
        }
        uint2 o0, o1;   // dims q*8 .. q*8+7 of node-row ro*8+g
        o0.x = f2bf(acc[0]) | (f2bf(acc[1]) << 16);
        o0.y = f2bf(acc[2]) | (f2bf(acc[3]) << 16);
        o1.x = f2bf(acc[4]) | (f2bf(acc[5]) << 16);
        o1.y = f2bf(acc[6]) | (f2bf(acc[7]) << 16);
        *(uint2*)&Ua[wid][ro * 8 + g][q * 8]     = o0;
        *(uint2*)&Ua[wid][ro * 8 + g][q * 8 + 4] = o1;
    }
    // W1^T frags: independent of LDS -> issue BEFORE the fence, overlap gather tail
    short8 wf1[8];
#pragma unroll
    for (int f = 0; f < 8; ++f) wf1[f] = Wp8[f * 64 + lane];
    __threadfence_block();   // same-wave LDS visibility (lgkmcnt), no inter-wave wait

    // ---- phase 2: GEMM1 + BN + ReLU -> Ub[wid] ----
    short8 t0 = *(const short8*)&Ua[wid][n15][quad * 8];        // k 0..31
    short8 t1 = *(const short8*)&Ua[wid][n15][32 + quad * 8];   // k 32..63
    {
        f32x4 c1[4];
#pragma unroll
        for (int mt = 0; mt < 4; ++mt) {
            c1[mt] = (f32x4){0.f, 0.f, 0.f, 0.f};
            c1[mt] = __builtin_amdgcn_mfma_f32_16x16x32_bf16(wf1[mt * 2 + 0], t0, c1[mt], 0, 0, 0);
            c1[mt] = __builtin_amdgcn_mfma_f32_16x16x32_bf16(wf1[mt * 2 + 1], t1, c1[mt], 0, 0, 0);
        }
        // BN constants computed here (not live during gather)
#pragma unroll
        for (int mt = 0; mt < 4; ++mt) {
            const int j0 = mt * 16 + quad * 4;
            f32x4 sc, sh;
#pragma unroll
            for (int r = 0; r < 4; ++r) {
                float s = gamma[j0 + r] * rsqrtf(rvar[j0 + r] + 1e-5f);
                sc[r] = s;
                sh[r] = (b1[j0 + r] - rmean[j0 + r]) * s + beta[j0 + r];
            }
            float u0 = fmaxf(c1[mt][0] * sc[0] + sh[0], 0.f);
            float u1 = fmaxf(c1[mt][1] * sc[1] + sh[1], 0.f);
            float u2 = fmaxf(c1[mt][2] * sc[2] + sh[2], 0.f);
            float u3 = fmaxf(c1[mt][3] * sc[3] + sh[3], 0.f);
            uint2 pk;
            pk.x = f2bf(u0) | (f2bf(u1) << 16);
            pk.y = f2bf(u2) | (f2bf(u3) << 16);
            *(uint2*)&Ub[wid][n15][mt * 16 + quad * 4] = pk;
        }
    }
    // W2 frags: issue before the fence, overlap phase-2 tail
    short8 wf2[8];
#pragma unroll
    for (int f = 0; f < 8; ++f) wf2[f] = Wp8[(8 + f) * 64 + lane];
    __threadfence_block();   // same-wave LDS visibility

    // ---- phase 3: GEMM2 + ReLU -> hb_next ----
    {
        short8 u0 = *(const short8*)&Ub[wid][n15][quad * 8];
        short8 u1 = *(const short8*)&Ub[wid][n15][32 + quad * 8];
        f32x4 c2[4];
#pragma unroll
        for (int tc = 0; tc < 4; ++tc) {
            c2[tc] = (f32x4){0.f, 0.f, 0.f, 0.f};
            c2[tc] = __builtin_amdgcn_mfma_f32_16x16x32_bf16(u0, wf2[tc * 2 + 0], c2[tc], 0, 0, 0);
            c2[tc] = __builtin_amdgcn_mfma_f32_16x16x32_bf16(u1, wf2[tc * 2 + 1], c2[tc], 0, 0, 0);
        }
#pragma unroll
        for (int tc = 0; tc < 4; ++tc) {
            const float bb2 = b2[tc * 16 + n15];
#pragma unroll
            for (int r = 0; r < 4; ++r) {
                float v = fmaxf(c2[tc][r] + bb2, 0.f);
                hbn[(size_t)(nb + quad * 4 + r) * 64 + tc * 16 + n15] = (ushort)f2bf(v);
            }
        }
    }
}

// ---------------- global_add_pool (batch sorted -> run-length + atomics) --------

__global__ void pool_kernel(const ushort* __restrict__ hb, const int* __restrict__ batch,
                            float* __restrict__ pooled, int n) {
    const int lane = threadIdx.x & 63;
    const int wid  = threadIdx.x >> 6;
    const int wave = blockIdx.x * 4 + wid;
    const int nwaves = gridDim.x * 4;
    const int per = (n + nwaves - 1) / nwaves;
    const int a = wave * per;
    const int b = min(a + per, n);
    if (a >= b) return;
    int cur = batch[a];
    float sum = 0.0f;
    for (int i = a; i < b; ++i) {
        int g = batch[i];
        if (g != cur) {
            atomicAdd(&pooled[cur * DIM + lane], sum);
            sum = 0.0f;
            cur = g;
        }
        sum += __uint_as_float(((uint)hb[(size_t)i * DIM + lane]) << 16);
    }
    atomicAdd(&pooled[cur * DIM + lane], sum);
}

// ---------------- head: relu(pooled@lin1+b1) @ lin2 + b2 ----------------

__global__ void head_kernel(const float* __restrict__ pooled,
                            const float* __restrict__ w1, const float* __restrict__ b1,
                            const float* __restrict__ w2, const float* __restrict__ b2,
                            float* __restrict__ out) {
    const int g = blockIdx.x;
    const int lane = threadIdx.x;  // 64 threads = 1 wave
    __shared__ float pl[DIM];
    __shared__ float y1l[DIM];
    pl[lane] = pooled[g * DIM + lane];
    __syncthreads();
    float y = b1[lane];
#pragma unroll
    for (int d = 0; d < DIM; ++d) y += pl[d] * w1[d * DIM + lane];
    y1l[lane] = fmaxf(y, 0.0f);
    __syncthreads();
    if (lane < OUT_DIM) {
        float y2 = b2[lane];
#pragma unroll
        for (int d = 0; d < DIM; ++d) y2 += y1l[d] * w2[d * OUT_DIM + lane];
        out[g * OUT_DIM + lane] = y2;
    }
}

// ---------------- launch ----------------

extern "C" void kernel_launch(void* const* d_in, const int* in_sizes, int n_in,
                              void* d_out, int out_size, void* d_ws, size_t ws_size,
                              hipStream_t stream) {
    const float* x     = (const float*)d_in[0];
    const int*   eidx  = (const int*)  d_in[1];   // [2, N_EDGES]: src row then dst row
    const int*   batch = (const int*)  d_in[2];
    const float* W1    = (const float*)d_in[3];
    const float* b1    = (const float*)d_in[4];
    const float* gamma = (const float*)d_in[5];
    const float* beta  = (const float*)d_in[6];
    const float* rmean = (const float*)d_in[7];
    const float* rvar  = (const float*)d_in[8];
    const float* W2    = (const float*)d_in[9];
    const float* b2    = (const float*)d_in[10];
    const float* l1w   = (const float*)d_in[11];
    const float* l1b   = (const float*)d_in[12];
    const float* l2w   = (const float*)d_in[13];
    const float* l2b   = (const float*)d_in[14];
    float* out = (float*)d_out;

    // workspace layout (int-element offsets; 16B alignment preserved)
    const size_t C8 = (size_t)N_CHUNKS * N_RANGES * RANGE_SIZE;   // 7,340,032
    const size_t B8 = (size_t)N_CHUNKS * NODE_PAD;                // 7,340,032
    const size_t ROWS = (size_t)N_NODES + 1;      // +1 zero row for masked gather pad
    int* counts8   = (int*)d_ws;
    int* row_ptr   = counts8   + C8;              // 100352
    int* blockSums = row_ptr   + 100352;          // 256
    int* blockOffs = blockSums + 256;             // 256
    int* base8     = blockOffs + 256;             // B8
    int* col_idx   = base8     + B8;              // 1600000
    uint4* Wp      = (uint4*)(col_idx + 1600000); // 5120 uint4 = 80KB
    ushort* tb     = (ushort*)(Wp + 5120);        // (100000+1)*64 bf16  [ping]
    ushort* hb     = tb + ROWS * DIM;             // (100000+1)*64 bf16  [pong]
    float* pooled  = (float*)(hb + ROWS * DIM);   // 128*64 fp32

    const int* srcp = eidx;
    const int* dstp = eidx + N_EDGES;

    hipMemsetAsync(pooled, 0, N_GRAPHS * DIM * sizeof(float), stream);
    // zero pad row (index N_NODES) in BOTH ping-pong buffers; never written after
    hipMemsetAsync(tb + (size_t)N_NODES * DIM, 0, DIM * sizeof(ushort), stream);
    hipMemsetAsync(hb + (size_t)N_NODES * DIM, 0, DIM * sizeof(ushort), stream);

    cvt_kernel<<<(N_NODES * DIM / 4 + 255) / 256, 256, 0, stream>>>(x, hb, N_NODES * DIM / 4);
    repack_kernel<<<1, 640, 0, stream>>>(W1, W2, Wp);
    histo_kernel<<<N_CHUNKS * 8, 1024, 0, stream>>>(dstp, counts8);
    scanA_kernel<<<SCAN_NB, 256, 0, stream>>>(counts8, blockSums, N_NODES);
    scanB_kernel<<<1, 256, 0, stream>>>(blockSums, blockOffs, row_ptr);
    scanC_kernel<<<SCAN_NB, 256, 0, stream>>>(counts8, blockOffs, row_ptr, base8, N_NODES);
    fill_kernel<<<N_CHUNKS * 8, 1024, 0, stream>>>(srcp, dstp, base8, col_idx);

    const int ntiles = N_NODES / 16;             // 6250 16-node tiles (R7 config)
    const int layer_blocks = (ntiles + 3) / 4;   // 1563: one tile per wave
    ushort* cur = hb;
    ushort* nxt = tb;
    for (int l = 0; l < 5; ++l) {
        layer_kernel<<<layer_blocks, 256, 0, stream>>>(
            cur, nxt, row_ptr, col_idx, Wp + (size_t)l * 2 * 8 * 64,
            b1 + (size_t)l * DIM, gamma + (size_t)l * DIM, beta + (size_t)l * DIM,
            rmean + (size_t)l * DIM, rvar + (size_t)l * DIM, b2 + (size_t)l * DIM, ntiles);
        ushort* t = cur; cur = nxt; nxt = t;
    }
    pool_kernel<<<2048, 256, 0, stream>>>(cur, batch, pooled, N_NODES);
    head_kernel<<<N_GRAPHS, 64, 0, stream>>>(pooled, l1w, l1b, l2w, l2b, out);
}

// Round 11
// 358.146 us; speedup vs baseline: 1.1298x; 1.0299x over previous
//
#include <hip/hip_runtime.h>

#define N_NODES  100000
#define N_EDGES  1600000
#define DIM      64
#define N_GRAPHS 128
#define OUT_DIM  10
#define SCAN_NB    196
#define SCAN_CHUNK 512      // 196*512 = 100352 >= N_NODES
#define RANGE_BITS 13
#define RANGE_SIZE 8192     // R11: halved -> 32KB LDS -> 2 blocks/CU for histo/fill
#define N_RANGES   14       // 14*8192 = 114688 >= N_NODES
#define N_CHUNKS   32       // back to 32: scan structures identical to R7 (R10 lesson)
#define CHUNK_EDGES (N_EDGES / N_CHUNKS)   // 50000
#define NODE_PAD   (N_RANGES * RANGE_SIZE) // 114688 (unchanged)

typedef unsigned int uint;
typedef unsigned short ushort;
typedef __attribute__((ext_vector_type(8))) short short8;   // 8 bf16 = 4 VGPRs
typedef __attribute__((ext_vector_type(4))) float f32x4;

__device__ __forceinline__ uint f2bf(float x) {   // fp32 -> bf16 bits (RNE)
    uint b = __float_as_uint(x);
    b += 0x7fffu + ((b >> 16) & 1u);
    return b >> 16;
}

// ---------------- CSR build (R7 structure; finer ranges for 2 blocks/CU) -------
// R10 lesson: extra chunks double scan traffic (regressed). Splitting the RANGE
// axis instead keeps counts8/base8/scan costs IDENTICAL to R7 (32 loads/node)
// while halving LDS to 32KB -> 2x block residency for the latency-bound
// histo/fill. histo: chunk-co-located (XCD = c%8) -> chunk read once per XCD.

__global__ __launch_bounds__(1024) void histo_kernel(const int* __restrict__ dst,
                                                     int* __restrict__ counts8) {
    __shared__ int lds[RANGE_SIZE];
    const int c = blockIdx.x & (N_CHUNKS - 1);   // XCD = c%8: chunk co-located
    const int r = blockIdx.x >> 5;               // 0..13, grid exactly 448
    if (r >= N_RANGES) return;
    for (int j = threadIdx.x; j < RANGE_SIZE; j += 1024) lds[j] = 0;
    __syncthreads();
    const int beg = c * CHUNK_EDGES, end = beg + CHUNK_EDGES;
    for (int i0 = beg + threadIdx.x; i0 < end; i0 += 1024 * 8) {
        int d[8];                       // 8 coalesced loads in flight per thread
#pragma unroll
        for (int k = 0; k < 8; ++k) {
            const int i = i0 + k * 1024;
            d[k] = (i < end) ? dst[i] : -1;
        }
#pragma unroll
        for (int k = 0; k < 8; ++k)
            if ((d[k] >> RANGE_BITS) == r) atomicAdd(&lds[d[k] & (RANGE_SIZE - 1)], 1);
    }
    __syncthreads();
    int* outp = counts8 + (c * N_RANGES + r) * RANGE_SIZE;   // contiguous 32KB dump
    for (int j = threadIdx.x; j < RANGE_SIZE; j += 1024) outp[j] = lds[j];
}

__global__ void scanA_kernel(const int* __restrict__ counts8, int* __restrict__ blockSums, int n) {
    __shared__ int red[256];
    const int b = blockIdx.x, t = threadIdx.x;
    int s = 0;
#pragma unroll
    for (int k = 0; k < 2; ++k) {
        const int node = b * SCAN_CHUNK + t * 2 + k;
        if (node < n) {
            const int r = node >> RANGE_BITS, jj = node & (RANGE_SIZE - 1);
            for (int c = 0; c < N_CHUNKS; ++c)
                s += counts8[(c * N_RANGES + r) * RANGE_SIZE + jj];
        }
    }
    red[t] = s;
    __syncthreads();
    for (int off = 128; off > 0; off >>= 1) {
        if (t < off) red[t] += red[t + off];
        __syncthreads();
    }
    if (t == 0) blockSums[b] = red[0];
}

__global__ void scanB_kernel(const int* __restrict__ blockSums, int* __restrict__ blockOffs,
                             int* __restrict__ row_ptr) {
    __shared__ int sc[256];
    const int t = threadIdx.x;
    const int v = (t < SCAN_NB) ? blockSums[t] : 0;
    sc[t] = v;
    __syncthreads();
    for (int off = 1; off < 256; off <<= 1) {
        int u = (t >= off) ? sc[t - off] : 0;
        __syncthreads();
        sc[t] += u;
        __syncthreads();
    }
    if (t < SCAN_NB) blockOffs[t] = sc[t] - v;   // exclusive block offset
    if (t == 255) row_ptr[N_NODES] = sc[255];    // total == N_EDGES
}

// row_ptr + per-chunk slot bases base8[c][node] (R7 reg-array version, 32 ints)
__global__ void scanC_kernel(const int* __restrict__ counts8, const int* __restrict__ blockOffs,
                             int* __restrict__ row_ptr, int* __restrict__ base8, int n) {
    __shared__ int sc[256];
    const int b = blockIdx.x, t = threadIdx.x;
    const int node0 = b * SCAN_CHUNK + t * 2;
    int cnt0[N_CHUNKS], cnt1[N_CHUNKS];
    int tot0 = 0, tot1 = 0;
    if (node0 < n) {
        const int r = node0 >> RANGE_BITS, jj = node0 & (RANGE_SIZE - 1);
        for (int c = 0; c < N_CHUNKS; ++c) {
            cnt0[c] = counts8[(c * N_RANGES + r) * RANGE_SIZE + jj];
            tot0 += cnt0[c];
        }
    }
    if (node0 + 1 < n) {
        const int r = (node0 + 1) >> RANGE_BITS, jj = (node0 + 1) & (RANGE_SIZE - 1);
        for (int c = 0; c < N_CHUNKS; ++c) {
            cnt1[c] = counts8[(c * N_RANGES + r) * RANGE_SIZE + jj];
            tot1 += cnt1[c];
        }
    }
    const int s = tot0 + tot1;
    sc[t] = s;
    __syncthreads();
    for (int off = 1; off < 256; off <<= 1) {
        int u = (t >= off) ? sc[t - off] : 0;
        __syncthreads();
        sc[t] += u;
        __syncthreads();
    }
    const int pre = blockOffs[b] + sc[t] - s;    // exclusive prefix for node0
    if (node0 < n) {
        row_ptr[node0] = pre;
        int run = pre;
        for (int c = 0; c < N_CHUNKS; ++c) { base8[c * NODE_PAD + node0] = run; run += cnt0[c]; }
    }
    if (node0 + 1 < n) {
        const int pre1 = pre + tot0;
        row_ptr[node0 + 1] = pre1;
        int run = pre1;
        for (int c = 0; c < N_CHUNKS; ++c) { base8[c * NODE_PAD + node0 + 1] = run; run += cnt1[c]; }
    }
}

// fill: RANGE-co-located. Decode guarantees XCD = blockIdx%8 = r%8, so range
// r's ~460KB col_idx span accumulates in one L2 (ranges r and r+8 share an XCD;
// both spans fit 4MB). dst/src PLAIN cached (L3-served re-reads); base8 NT.
// Grid 512 (64 inactive): r = (blockIdx&7) + 8*(blockIdx>>8), c = (blockIdx>>3)&31.

__global__ __launch_bounds__(1024) void fill_kernel(const int* __restrict__ src,
                                                    const int* __restrict__ dst,
                                                    const int* __restrict__ base8,
                                                    int* __restrict__ col_idx) {
    __shared__ int lds[RANGE_SIZE];
    const int r = (blockIdx.x & 7) | ((blockIdx.x >> 8) << 3);   // XCD = r%8
    const int c = (blockIdx.x >> 3) & (N_CHUNKS - 1);
    if (r >= N_RANGES) return;
    const int* bp = base8 + c * NODE_PAD + r * RANGE_SIZE;
    for (int j = threadIdx.x; j < RANGE_SIZE; j += 1024)
        lds[j] = __builtin_nontemporal_load(&bp[j]);
    __syncthreads();
    const int beg = c * CHUNK_EDGES, end = beg + CHUNK_EDGES;
    for (int i0 = beg + threadIdx.x; i0 < end; i0 += 1024 * 8) {
        int d[8], s[8];                  // 16 coalesced loads in flight per thread
#pragma unroll
        for (int k = 0; k < 8; ++k) {
            const int i = i0 + k * 1024;
            d[k] = (i < end) ? dst[i] : -1;
            s[k] = (i < end) ? src[i] : 0;
        }
#pragma unroll
        for (int k = 0; k < 8; ++k) {
            if ((d[k] >> RANGE_BITS) == r) {
                int pos = atomicAdd(&lds[d[k] & (RANGE_SIZE - 1)], 1);
                col_idx[pos] = s[k];     // cached: L2-absorbed, merged write-back
            }
        }
    }
}

// ---------------- x (fp32) -> bf16 rows ----------------

__global__ void cvt_kernel(const float* __restrict__ x, ushort* __restrict__ xb, int n4) {
    int idx = blockIdx.x * blockDim.x + threadIdx.x;
    if (idx >= n4) return;
    float4 v = ((const float4*)x)[idx];
    uint2 o;
    o.x = f2bf(v.x) | (f2bf(v.y) << 16);
    o.y = f2bf(v.z) | (f2bf(v.w) << 16);
    ((uint2*)xb)[idx] = o;
}

// ---------------- Weight repack: MFMA fragment layouts, once per launch ----------

__global__ void repack_kernel(const float* __restrict__ W1, const float* __restrict__ W2,
                              uint4* __restrict__ Wp) {
    const int wave = (blockIdx.x * blockDim.x + threadIdx.x) >> 6;
    if (wave >= 10) return;
    const int layer = wave >> 1;
    const float* W = (wave & 1) ? (W2 + layer * 4096) : (W1 + layer * 4096);
    const int lane = threadIdx.x & 63;
    const int n15 = lane & 15, quad = lane >> 4;
#pragma unroll
    for (int f = 0; f < 8; ++f) {
        const int outer = f >> 1, h = f & 1;
        uint p[4];
#pragma unroll
        for (int pj = 0; pj < 4; ++pj) {
            const int k0 = h * 32 + quad * 8 + 2 * pj;
            uint lo = f2bf(W[k0 * 64 + outer * 16 + n15]);
            uint hi = f2bf(W[(k0 + 1) * 64 + outer * 16 + n15]);
            p[pj] = lo | (hi << 16);
        }
        Wp[(wave * 8 + f) * 64 + lane] = make_uint4(p[0], p[1], p[2], p[3]);
    }
}

// ---------------- Fused GIN layer (R7 config: 16-node tiles, verified 345us) ----
// Wave-independent (no barriers, per-wave LDS slices + threadfence), masked
// 8-wide batches with zero-row pad, software-pipelined col_idx, W-frags hoisted
// above the threadfences. R8 proved 8-node tiles regress (2x MLP overhead).

__device__ __forceinline__ void add_unpack(float acc[8], uint4 v) {
    acc[0] += __uint_as_float(v.x << 16);
    acc[1] += __uint_as_float(v.x & 0xffff0000u);
    acc[2] += __uint_as_float(v.y << 16);
    acc[3] += __uint_as_float(v.y & 0xffff0000u);
    acc[4] += __uint_as_float(v.z << 16);
    acc[5] += __uint_as_float(v.z & 0xffff0000u);
    acc[6] += __uint_as_float(v.w << 16);
    acc[7] += __uint_as_float(v.w & 0xffff0000u);
}

__global__ __launch_bounds__(256) void layer_kernel(
    const ushort* __restrict__ hbp, ushort* __restrict__ hbn,
    const int* __restrict__ row_ptr, const int* __restrict__ col_idx,
    const uint4* __restrict__ Wp,   // layer frags: [0..7]=W1^T, [8..15]=W2
    const float* __restrict__ b1, const float* __restrict__ gamma,
    const float* __restrict__ beta, const float* __restrict__ rmean,
    const float* __restrict__ rvar, const float* __restrict__ b2, int ntiles)
{
    __shared__ __align__(16) ushort Ua[4][16][72];   // agg out / GEMM1 in (per-wave slice)
    __shared__ __align__(16) ushort Ub[4][16][72];   // GEMM1 out / GEMM2 in (per-wave slice)
    const uint4* __restrict__ hb4 = (const uint4*)hbp;   // row = 8 uint4
    const int lane = threadIdx.x & 63;
    const int wid  = threadIdx.x >> 6;
    const int n15  = lane & 15, quad = lane >> 4;
    const int g = lane >> 3;     // node slot within round
    const int q = lane & 7;      // 16B chunk within row
    const short8* Wp8 = (const short8*)Wp;

    const int tile = blockIdx.x * 4 + wid;   // one 16-node tile per wave
    if (tile >= ntiles) return;              // whole-wave exit; no barriers anywhere
    const int nb = tile * 16;

    // ---- phase 1: aggregate 16 nodes -> Ua[wid] (bf16, node-row layout) ----
    for (int ro = 0; ro < 2; ++ro) {
        const int i = nb + ro * 8 + g;
        const int rp0 = row_ptr[i];
        const int rp1 = row_ptr[i + 1];
        float acc[8];
        {   // self term (eps = 0)
            uint4 v = hb4[(size_t)i * 8 + q];
            acc[0] = __uint_as_float(v.x << 16);
            acc[1] = __uint_as_float(v.x & 0xffff0000u);
            acc[2] = __uint_as_float(v.y << 16);
            acc[3] = __uint_as_float(v.y & 0xffff0000u);
            acc[4] = __uint_as_float(v.z << 16);
            acc[5] = __uint_as_float(v.z & 0xffff0000u);
            acc[6] = __uint_as_float(v.w << 16);
            acc[7] = __uint_as_float(v.w & 0xffff0000u);
        }
        const int nbat = (rp1 - rp0 + 7) >> 3;   // uniform full batches, masked tail
        int ixn[8];   // pipelined index buffer (batch b+1 loads during batch b)
#pragma unroll
        for (int k = 0; k < 8; ++k)
            ixn[k] = col_idx[max(min(rp0 + k, rp1 - 1), 0)];   // max: deg-0 safety
        for (int b = 0; b < nbat; ++b) {
            const int e0 = rp0 + b * 8;
            int ix[8];
#pragma unroll
            for (int k = 0; k < 8; ++k)
                ix[k] = (e0 + k < rp1) ? ixn[k] : N_NODES;     // pad -> zero row
#pragma unroll
            for (int k = 0; k < 8; ++k)                        // prefetch batch b+1
                ixn[k] = col_idx[min(e0 + 8 + k, rp1 - 1)];    // rp1>=1 here: safe
            uint4 v[8];
#pragma unroll
            for (int k = 0; k < 8; ++k) v[k] = hb4[(size_t)ix[k] * 8 + q];
#pragma unroll
            for (int k = 0; k < 8; ++k) add_unpack(acc, v[k]);
        }
        uint2 o0, o1;   // dims q*8 .. q*8+7 of node-row ro*8+g
        o0.x = f2bf(acc[0]) | (f2bf(acc[1]) << 16);
        o0.y = f2bf(acc[2]) | (f2bf(acc[3]) << 16);
        o1.x = f2bf(acc[4]) | (f2bf(acc[5]) << 16);
        o1.y = f2bf(acc[6]) | (f2bf(acc[7]) << 16);
        *(uint2*)&Ua[wid][ro * 8 + g][q * 8]     = o0;
        *(uint2*)&Ua[wid][ro * 8 + g][q * 8 + 4] = o1;
    }
    // W1^T frags: independent of LDS -> issue BEFORE the fence, overlap gather tail
    short8 wf1[8];
#pragma unroll
    for (int f = 0; f < 8; ++f) wf1[f] = Wp8[f * 64 + lane];
    __threadfence_block();   // same-wave LDS visibility (lgkmcnt), no inter-wave wait

    // ---- phase 2: GEMM1 + BN + ReLU -> Ub[wid] ----
    short8 t0 = *(const short8*)&Ua[wid][n15][quad * 8];        // k 0..31
    short8 t1 = *(const short8*)&Ua[wid][n15][32 + quad * 8];   // k 32..63
    {
        f32x4 c1[4];
#pragma unroll
        for (int mt = 0; mt < 4; ++mt) {
            c1[mt] = (f32x4){0.f, 0.f, 0.f, 0.f};
            c1[mt] = __builtin_amdgcn_mfma_f32_16x16x32_bf16(wf1[mt * 2 + 0], t0, c1[mt], 0, 0, 0);
            c1[mt] = __builtin_amdgcn_mfma_f32_16x16x32_bf16(wf1[mt * 2 + 1], t1, c1[mt], 0, 0, 0);
        }
        // BN constants computed here (not live during gather)
#pragma unroll
        for (int mt = 0; mt < 4; ++mt) {
            const int j0 = mt * 16 + quad * 4;
            f32x4 sc, sh;
#pragma unroll
            for (int r = 0; r < 4; ++r) {
                float s = gamma[j0 + r] * rsqrtf(rvar[j0 + r] + 1e-5f);
                sc[r] = s;
                sh[r] = (b1[j0 + r] - rmean[j0 + r]) * s + beta[j0 + r];
            }
            float u0 = fmaxf(c1[mt][0] * sc[0] + sh[0], 0.f);
            float u1 = fmaxf(c1[mt][1] * sc[1] + sh[1], 0.f);
            float u2 = fmaxf(c1[mt][2] * sc[2] + sh[2], 0.f);
            float u3 = fmaxf(c1[mt][3] * sc[3] + sh[3], 0.f);
            uint2 pk;
            pk.x = f2bf(u0) | (f2bf(u1) << 16);
            pk.y = f2bf(u2) | (f2bf(u3) << 16);
            *(uint2*)&Ub[wid][n15][mt * 16 + quad * 4] = pk;
        }
    }
    // W2 frags: issue before the fence, overlap phase-2 tail
    short8 wf2[8];
#pragma unroll
    for (int f = 0; f < 8; ++f) wf2[f] = Wp8[(8 + f) * 64 + lane];
    __threadfence_block();   // same-wave LDS visibility

    // ---- phase 3: GEMM2 + ReLU -> hb_next ----
    {
        short8 u0 = *(const short8*)&Ub[wid][n15][quad * 8];
        short8 u1 = *(const short8*)&Ub[wid][n15][32 + quad * 8];
        f32x4 c2[4];
#pragma unroll
        for (int tc = 0; tc < 4; ++tc) {
            c2[tc] = (f32x4){0.f, 0.f, 0.f, 0.f};
            c2[tc] = __builtin_amdgcn_mfma_f32_16x16x32_bf16(u0, wf2[tc * 2 + 0], c2[tc], 0, 0, 0);
            c2[tc] = __builtin_amdgcn_mfma_f32_16x16x32_bf16(u1, wf2[tc * 2 + 1], c2[tc], 0, 0, 0);
        }
#pragma unroll
        for (int tc = 0; tc < 4; ++tc) {
            const float bb2 = b2[tc * 16 + n15];
#pragma unroll
            for (int r = 0; r < 4; ++r) {
                float v = fmaxf(c2[tc][r] + bb2, 0.f);
                hbn[(size_t)(nb + quad * 4 + r) * 64 + tc * 16 + n15] = (ushort)f2bf(v);
            }
        }
    }
}

// ---------------- global_add_pool (batch sorted -> run-length + atomics) --------

__global__ void pool_kernel(const ushort* __restrict__ hb, const int* __restrict__ batch,
                            float* __restrict__ pooled, int n) {
    const int lane = threadIdx.x & 63;
    const int wid  = threadIdx.x >> 6;
    const int wave = blockIdx.x * 4 + wid;
    const int nwaves = gridDim.x * 4;
    const int per = (n + nwaves - 1) / nwaves;
    const int a = wave * per;
    const int b = min(a + per, n);
    if (a >= b) return;
    int cur = batch[a];
    float sum = 0.0f;
    for (int i = a; i < b; ++i) {
        int g = batch[i];
        if (g != cur) {
            atomicAdd(&pooled[cur * DIM + lane], sum);
            sum = 0.0f;
            cur = g;
        }
        sum += __uint_as_float(((uint)hb[(size_t)i * DIM + lane]) << 16);
    }
    atomicAdd(&pooled[cur * DIM + lane], sum);
}

// ---------------- head: relu(pooled@lin1+b1) @ lin2 + b2 ----------------

__global__ void head_kernel(const float* __restrict__ pooled,
                            const float* __restrict__ w1, const float* __restrict__ b1,
                            const float* __restrict__ w2, const float* __restrict__ b2,
                            float* __restrict__ out) {
    const int g = blockIdx.x;
    const int lane = threadIdx.x;  // 64 threads = 1 wave
    __shared__ float pl[DIM];
    __shared__ float y1l[DIM];
    pl[lane] = pooled[g * DIM + lane];
    __syncthreads();
    float y = b1[lane];
#pragma unroll
    for (int d = 0; d < DIM; ++d) y += pl[d] * w1[d * DIM + lane];
    y1l[lane] = fmaxf(y, 0.0f);
    __syncthreads();
    if (lane < OUT_DIM) {
        float y2 = b2[lane];
#pragma unroll
        for (int d = 0; d < DIM; ++d) y2 += y1l[d] * w2[d * OUT_DIM + lane];
        out[g * OUT_DIM + lane] = y2;
    }
}

// ---------------- launch ----------------

extern "C" void kernel_launch(void* const* d_in, const int* in_sizes, int n_in,
                              void* d_out, int out_size, void* d_ws, size_t ws_size,
                              hipStream_t stream) {
    const float* x     = (const float*)d_in[0];
    const int*   eidx  = (const int*)  d_in[1];   // [2, N_EDGES]: src row then dst row
    const int*   batch = (const int*)  d_in[2];
    const float* W1    = (const float*)d_in[3];
    const float* b1    = (const float*)d_in[4];
    const float* gamma = (const float*)d_in[5];
    const float* beta  = (const float*)d_in[6];
    const float* rmean = (const float*)d_in[7];
    const float* rvar  = (const float*)d_in[8];
    const float* W2    = (const float*)d_in[9];
    const float* b2    = (const float*)d_in[10];
    const float* l1w   = (const float*)d_in[11];
    const float* l1b   = (const float*)d_in[12];
    const float* l2w   = (const float*)d_in[13];
    const float* l2b   = (const float*)d_in[14];
    float* out = (float*)d_out;

    // workspace layout (int-element offsets; 16B alignment preserved)
    const size_t C8 = (size_t)N_CHUNKS * N_RANGES * RANGE_SIZE;   // 3,670,016 (= R7)
    const size_t B8 = (size_t)N_CHUNKS * NODE_PAD;                // 3,670,016 (= R7)
    const size_t ROWS = (size_t)N_NODES + 1;      // +1 zero row for masked gather pad
    int* counts8   = (int*)d_ws;
    int* row_ptr   = counts8   + C8;              // 100352
    int* blockSums = row_ptr   + 100352;          // 256
    int* blockOffs = blockSums + 256;             // 256
    int* base8     = blockOffs + 256;             // B8
    int* col_idx   = base8     + B8;              // 1600000
    uint4* Wp      = (uint4*)(col_idx + 1600000); // 5120 uint4 = 80KB
    ushort* tb     = (ushort*)(Wp + 5120);        // (100000+1)*64 bf16  [ping]
    ushort* hb     = tb + ROWS * DIM;             // (100000+1)*64 bf16  [pong]
    float* pooled  = (float*)(hb + ROWS * DIM);   // 128*64 fp32

    const int* srcp = eidx;
    const int* dstp = eidx + N_EDGES;

    hipMemsetAsync(pooled, 0, N_GRAPHS * DIM * sizeof(float), stream);
    // zero pad row (index N_NODES) in BOTH ping-pong buffers; never written after
    hipMemsetAsync(tb + (size_t)N_NODES * DIM, 0, DIM * sizeof(ushort), stream);
    hipMemsetAsync(hb + (size_t)N_NODES * DIM, 0, DIM * sizeof(ushort), stream);

    cvt_kernel<<<(N_NODES * DIM / 4 + 255) / 256, 256, 0, stream>>>(x, hb, N_NODES * DIM / 4);
    repack_kernel<<<1, 640, 0, stream>>>(W1, W2, Wp);
    histo_kernel<<<N_CHUNKS * N_RANGES, 1024, 0, stream>>>(dstp, counts8);   // 448
    scanA_kernel<<<SCAN_NB, 256, 0, stream>>>(counts8, blockSums, N_NODES);
    scanB_kernel<<<1, 256, 0, stream>>>(blockSums, blockOffs, row_ptr);
    scanC_kernel<<<SCAN_NB, 256, 0, stream>>>(counts8, blockOffs, row_ptr, base8, N_NODES);
    fill_kernel<<<512, 1024, 0, stream>>>(srcp, dstp, base8, col_idx);       // 448 active

    const int ntiles = N_NODES / 16;             // 6250 16-node tiles (R7 config)
    const int layer_blocks = (ntiles + 3) / 4;   // 1563: one tile per wave
    ushort* cur = hb;
    ushort* nxt = tb;
    for (int l = 0; l < 5; ++l) {
        layer_kernel<<<layer_blocks, 256, 0, stream>>>(
            cur, nxt, row_ptr, col_idx, Wp + (size_t)l * 2 * 8 * 64,
            b1 + (size_t)l * DIM, gamma + (size_t)l * DIM, beta + (size_t)l * DIM,
            rmean + (size_t)l * DIM, rvar + (size_t)l * DIM, b2 + (size_t)l * DIM, ntiles);
        ushort* t = cur; cur = nxt; nxt = t;
    }
    pool_kernel<<<2048, 256, 0, stream>>>(cur, batch, pooled, N_NODES);
    head_kernel<<<N_GRAPHS, 64, 0, stream>>>(pooled, l1w, l1b, l2w, l2b, out);
}

// Round 12
// 345.113 us; speedup vs baseline: 1.1725x; 1.0378x over previous
//
#include <hip/hip_runtime.h>

#define N_NODES  100000
#define N_EDGES  1600000
#define DIM      64
#define N_GRAPHS 128
#define OUT_DIM  10
#define SCAN_NB    196
#define SCAN_CHUNK 512      // 196*512 = 100352 >= N_NODES
#define RANGE_BITS 14
#define RANGE_SIZE 16384    // nodes per dst-range (R7 optimum: passes/scan/locality triangle)
#define N_RANGES   7        // 7*16384 = 114688 >= N_NODES
#define N_CHUNKS   32
#define CHUNK_EDGES (N_EDGES / N_CHUNKS)   // 50000
#define NODE_PAD   (N_RANGES * RANGE_SIZE) // 114688

typedef unsigned int uint;
typedef unsigned short ushort;
typedef __attribute__((ext_vector_type(8))) short short8;   // 8 bf16 = 4 VGPRs
typedef __attribute__((ext_vector_type(4))) float f32x4;

__device__ __forceinline__ uint f2bf(float x) {   // fp32 -> bf16 bits (RNE)
    uint b = __float_as_uint(x);
    b += 0x7fffu + ((b >> 16) & 1u);
    return b >> 16;
}

// ---------------- CSR build (R7 structure + unroll-16 ILP) ----------------
// CSR structure search concluded: R9 global cursors (write thrash), R10 more
// chunks (2x scan), R11 more ranges (2x edge passes) all regressed — R7's
// {7 ranges, 32 chunks, LDS cursors} is the structural optimum. This round:
// pure ILP inside it. histo/fill are latency-regime (VALU 4.6%, occ 25%,
// HBM 16%) with ~6 dependent epochs/chunk at unroll 8 -> unroll 16 halves
// epochs, no structural/traffic change. Pre-commit: null => L3-stream ceiling.
// histo: chunk-co-located (XCD = c%8) -> chunk's dst read once per XCD.

__global__ __launch_bounds__(1024) void histo_kernel(const int* __restrict__ dst,
                                                     int* __restrict__ counts8) {
    __shared__ int lds[RANGE_SIZE];
    const int c = blockIdx.x & (N_CHUNKS - 1);
    const int r = blockIdx.x >> 5;
    if (r >= N_RANGES) return;
    for (int j = threadIdx.x; j < RANGE_SIZE; j += 1024) lds[j] = 0;
    __syncthreads();
    const int beg = c * CHUNK_EDGES, end = beg + CHUNK_EDGES;
    for (int i0 = beg + threadIdx.x; i0 < end; i0 += 1024 * 16) {
        int d[16];                      // 16 coalesced loads in flight per thread
#pragma unroll
        for (int k = 0; k < 16; ++k) {
            const int i = i0 + k * 1024;
            d[k] = (i < end) ? dst[i] : -1;
        }
#pragma unroll
        for (int k = 0; k < 16; ++k)
            if ((d[k] >> RANGE_BITS) == r) atomicAdd(&lds[d[k] & (RANGE_SIZE - 1)], 1);
    }
    __syncthreads();
    int* outp = counts8 + (c * N_RANGES + r) * RANGE_SIZE;   // contiguous 64KB dump
    for (int j = threadIdx.x; j < RANGE_SIZE; j += 1024) outp[j] = lds[j];
}

__global__ void scanA_kernel(const int* __restrict__ counts8, int* __restrict__ blockSums, int n) {
    __shared__ int red[256];
    const int b = blockIdx.x, t = threadIdx.x;
    int s = 0;
#pragma unroll
    for (int k = 0; k < 2; ++k) {
        const int node = b * SCAN_CHUNK + t * 2 + k;
        if (node < n) {
            const int r = node >> RANGE_BITS, jj = node & (RANGE_SIZE - 1);
            for (int c = 0; c < N_CHUNKS; ++c)
                s += counts8[(c * N_RANGES + r) * RANGE_SIZE + jj];
        }
    }
    red[t] = s;
    __syncthreads();
    for (int off = 128; off > 0; off >>= 1) {
        if (t < off) red[t] += red[t + off];
        __syncthreads();
    }
    if (t == 0) blockSums[b] = red[0];
}

__global__ void scanB_kernel(const int* __restrict__ blockSums, int* __restrict__ blockOffs,
                             int* __restrict__ row_ptr) {
    __shared__ int sc[256];
    const int t = threadIdx.x;
    const int v = (t < SCAN_NB) ? blockSums[t] : 0;
    sc[t] = v;
    __syncthreads();
    for (int off = 1; off < 256; off <<= 1) {
        int u = (t >= off) ? sc[t - off] : 0;
        __syncthreads();
        sc[t] += u;
        __syncthreads();
    }
    if (t < SCAN_NB) blockOffs[t] = sc[t] - v;   // exclusive block offset
    if (t == 255) row_ptr[N_NODES] = sc[255];    // total == N_EDGES
}

// row_ptr + per-chunk slot bases base8[c][node]
__global__ void scanC_kernel(const int* __restrict__ counts8, const int* __restrict__ blockOffs,
                             int* __restrict__ row_ptr, int* __restrict__ base8, int n) {
    __shared__ int sc[256];
    const int b = blockIdx.x, t = threadIdx.x;
    const int node0 = b * SCAN_CHUNK + t * 2;
    int cnt0[N_CHUNKS], cnt1[N_CHUNKS];
    int tot0 = 0, tot1 = 0;
    if (node0 < n) {
        const int r = node0 >> RANGE_BITS, jj = node0 & (RANGE_SIZE - 1);
        for (int c = 0; c < N_CHUNKS; ++c) {
            cnt0[c] = counts8[(c * N_RANGES + r) * RANGE_SIZE + jj];
            tot0 += cnt0[c];
        }
    }
    if (node0 + 1 < n) {
        const int r = (node0 + 1) >> RANGE_BITS, jj = (node0 + 1) & (RANGE_SIZE - 1);
        for (int c = 0; c < N_CHUNKS; ++c) {
            cnt1[c] = counts8[(c * N_RANGES + r) * RANGE_SIZE + jj];
            tot1 += cnt1[c];
        }
    }
    const int s = tot0 + tot1;
    sc[t] = s;
    __syncthreads();
    for (int off = 1; off < 256; off <<= 1) {
        int u = (t >= off) ? sc[t - off] : 0;
        __syncthreads();
        sc[t] += u;
        __syncthreads();
    }
    const int pre = blockOffs[b] + sc[t] - s;    // exclusive prefix for node0
    if (node0 < n) {
        row_ptr[node0] = pre;
        int run = pre;
        for (int c = 0; c < N_CHUNKS; ++c) { base8[c * NODE_PAD + node0] = run; run += cnt0[c]; }
    }
    if (node0 + 1 < n) {
        const int pre1 = pre + tot0;
        row_ptr[node0 + 1] = pre1;
        int run = pre1;
        for (int c = 0; c < N_CHUNKS; ++c) { base8[c * NODE_PAD + node0 + 1] = run; run += cnt1[c]; }
    }
}

// fill: RANGE-co-located (XCD = blockIdx%8 = r): range r's ~914KB col_idx span
// accumulates in ONE L2 -> near-full-line write-backs (R1: WRITE 59.8->6.5MB).
// dst/src PLAIN cached (L3-served re-reads); base8 NT (read once, one XCD).

__global__ __launch_bounds__(1024) void fill_kernel(const int* __restrict__ src,
                                                    const int* __restrict__ dst,
                                                    const int* __restrict__ base8,
                                                    int* __restrict__ col_idx) {
    __shared__ int lds[RANGE_SIZE];
    const int r = blockIdx.x & 7;        // XCD id == r  -> write-side co-location
    const int c = blockIdx.x >> 3;
    if (r >= N_RANGES) return;
    const int* bp = base8 + c * NODE_PAD + r * RANGE_SIZE;
    for (int j = threadIdx.x; j < RANGE_SIZE; j += 1024)
        lds[j] = __builtin_nontemporal_load(&bp[j]);
    __syncthreads();
    const int beg = c * CHUNK_EDGES, end = beg + CHUNK_EDGES;
    for (int i0 = beg + threadIdx.x; i0 < end; i0 += 1024 * 16) {
        int d[16], s[16];                // 32 coalesced loads in flight per thread
#pragma unroll
        for (int k = 0; k < 16; ++k) {
            const int i = i0 + k * 1024;
            d[k] = (i < end) ? dst[i] : -1;
            s[k] = (i < end) ? src[i] : 0;
        }
#pragma unroll
        for (int k = 0; k < 16; ++k) {
            if ((d[k] >> RANGE_BITS) == r) {
                int pos = atomicAdd(&lds[d[k] & (RANGE_SIZE - 1)], 1);
                col_idx[pos] = s[k];     // cached: L2-absorbed, merged write-back
            }
        }
    }
}

// ---------------- x (fp32) -> bf16 rows ----------------

__global__ void cvt_kernel(const float* __restrict__ x, ushort* __restrict__ xb, int n4) {
    int idx = blockIdx.x * blockDim.x + threadIdx.x;
    if (idx >= n4) return;
    float4 v = ((const float4*)x)[idx];
    uint2 o;
    o.x = f2bf(v.x) | (f2bf(v.y) << 16);
    o.y = f2bf(v.z) | (f2bf(v.w) << 16);
    ((uint2*)xb)[idx] = o;
}

// ---------------- Weight repack: MFMA fragment layouts, once per launch ----------

__global__ void repack_kernel(const float* __restrict__ W1, const float* __restrict__ W2,
                              uint4* __restrict__ Wp) {
    const int wave = (blockIdx.x * blockDim.x + threadIdx.x) >> 6;
    if (wave >= 10) return;
    const int layer = wave >> 1;
    const float* W = (wave & 1) ? (W2 + layer * 4096) : (W1 + layer * 4096);
    const int lane = threadIdx.x & 63;
    const int n15 = lane & 15, quad = lane >> 4;
#pragma unroll
    for (int f = 0; f < 8; ++f) {
        const int outer = f >> 1, h = f & 1;
        uint p[4];
#pragma unroll
        for (int pj = 0; pj < 4; ++pj) {
            const int k0 = h * 32 + quad * 8 + 2 * pj;
            uint lo = f2bf(W[k0 * 64 + outer * 16 + n15]);
            uint hi = f2bf(W[(k0 + 1) * 64 + outer * 16 + n15]);
            p[pj] = lo | (hi << 16);
        }
        Wp[(wave * 8 + f) * 64 + lane] = make_uint4(p[0], p[1], p[2], p[3]);
    }
}

// ---------------- Fused GIN layer (R7 config: 16-node tiles, verified 345us) ----
// Wave-independent (no barriers, per-wave LDS slices + threadfence), masked
// 8-wide batches with zero-row pad, software-pipelined col_idx, W-frags hoisted
// above the threadfences. R8 proved 8-node tiles regress (2x MLP overhead).

__device__ __forceinline__ void add_unpack(float acc[8], uint4 v) {
    acc[0] += __uint_as_float(v.x << 16);
    acc[1] += __uint_as_float(v.x & 0xffff0000u);
    acc[2] += __uint_as_float(v.y << 16);
    acc[3] += __uint_as_float(v.y & 0xffff0000u);
    acc[4] += __uint_as_float(v.z << 16);
    acc[5] += __uint_as_float(v.z & 0xffff0000u);
    acc[6] += __uint_as_float(v.w << 16);
    acc[7] += __uint_as_float(v.w & 0xffff0000u);
}

__global__ __launch_bounds__(256) void layer_kernel(
    const ushort* __restrict__ hbp, ushort* __restrict__ hbn,
    const int* __restrict__ row_ptr, const int* __restrict__ col_idx,
    const uint4* __restrict__ Wp,   // layer frags: [0..7]=W1^T, [8..15]=W2
    const float* __restrict__ b1, const float* __restrict__ gamma,
    const float* __restrict__ beta, const float* __restrict__ rmean,
    const float* __restrict__ rvar, const float* __restrict__ b2, int ntiles)
{
    __shared__ __align__(16) ushort Ua[4][16][72];   // agg out / GEMM1 in (per-wave slice)
    __shared__ __align__(16) ushort Ub[4][16][72];   // GEMM1 out / GEMM2 in (per-wave slice)
    const uint4* __restrict__ hb4 = (const uint4*)hbp;   // row = 8 uint4
    const int lane = threadIdx.x & 63;
    const int wid  = threadIdx.x >> 6;
    const int n15  = lane & 15, quad = lane >> 4;
    const int g = lane >> 3;     // node slot within round
    const int q = lane & 7;      // 16B chunk within row
    const short8* Wp8 = (const short8*)Wp;

    const int tile = blockIdx.x * 4 + wid;   // one 16-node tile per wave
    if (tile >= ntiles) return;              // whole-wave exit; no barriers anywhere
    const int nb = tile * 16;

    // ---- phase 1: aggregate 16 nodes -> Ua[wid] (bf16, node-row layout) ----
    for (int ro = 0; ro < 2; ++ro) {
        const int i = nb + ro * 8 + g;
        const int rp0 = row_ptr[i];
        const int rp1 = row_ptr[i + 1];
        float acc[8];
        {   // self term (eps = 0)
            uint4 v = hb4[(size_t)i * 8 + q];
            acc[0] = __uint_as_float(v.x << 16);
            acc[1] = __uint_as_float(v.x & 0xffff0000u);
            acc[2] = __uint_as_float(v.y << 16);
            acc[3] = __uint_as_float(v.y & 0xffff0000u);
            acc[4] = __uint_as_float(v.z << 16);
            acc[5] = __uint_as_float(v.z & 0xffff0000u);
            acc[6] = __uint_as_float(v.w << 16);
            acc[7] = __uint_as_float(v.w & 0xffff0000u);
        }
        const int nbat = (rp1 - rp0 + 7) >> 3;   // uniform full batches, masked tail
        int ixn[8];   // pipelined index buffer (batch b+1 loads during batch b)
#pragma unroll
        for (int k = 0; k < 8; ++k)
            ixn[k] = col_idx[max(min(rp0 + k, rp1 - 1), 0)];   // max: deg-0 safety
        for (int b = 0; b < nbat; ++b) {
            const int e0 = rp0 + b * 8;
            int ix[8];
#pragma unroll
            for (int k = 0; k < 8; ++k)
                ix[k] = (e0 + k < rp1) ? ixn[k] : N_NODES;     // pad -> zero row
#pragma unroll
            for (int k = 0; k < 8; ++k)                        // prefetch batch b+1
                ixn[k] = col_idx[min(e0 + 8 + k, rp1 - 1)];    // rp1>=1 here: safe
            uint4 v[8];
#pragma unroll
            for (int k = 0; k < 8; ++k) v[k] = hb4[(size_t)ix[k] * 8 + q];
#pragma unroll
            for (int k = 0; k < 8; ++k) add_unpack(acc, v[k]);
        }
        uint2 o0, o1;   // dims q*8 .. q*8+7 of node-row ro*8+g
        o0.x = f2bf(acc[0]) | (f2bf(acc[1]) << 16);
        o0.y = f2bf(acc[2]) | (f2bf(acc[3]) << 16);
        o1.x = f2bf(acc[4]) | (f2bf(acc[5]) << 16);
        o1.y = f2bf(acc[6]) | (f2bf(acc[7]) << 16);
        *(uint2*)&Ua[wid][ro * 8 + g][q * 8]     = o0;
        *(uint2*)&Ua[wid][ro * 8 + g][q * 8 + 4] = o1;
    }
    // W1^T frags: independent of LDS -> issue BEFORE the fence, overlap gather tail
    short8 wf1[8];
#pragma unroll
    for (int f = 0; f < 8; ++f) wf1[f] = Wp8[f * 64 + lane];
    __threadfence_block();   // same-wave LDS visibility (lgkmcnt), no inter-wave wait

    // ---- phase 2: GEMM1 + BN + ReLU -> Ub[wid] ----
    short8 t0 = *(const short8*)&Ua[wid][n15][quad * 8];        // k 0..31
    short8 t1 = *(const short8*)&Ua[wid][n15][32 + quad * 8];   // k 32..63
    {
        f32x4 c1[4];
#pragma unroll
        for (int mt = 0; mt < 4; ++mt) {
            c1[mt] = (f32x4){0.f, 0.f, 0.f, 0.f};
            c1[mt] = __builtin_amdgcn_mfma_f32_16x16x32_bf16(wf1[mt * 2 + 0], t0, c1[mt], 0, 0, 0);
            c1[mt] = __builtin_amdgcn_mfma_f32_16x16x32_bf16(wf1[mt * 2 + 1], t1, c1[mt], 0, 0, 0);
        }
        // BN constants computed here (not live during gather)
#pragma unroll
        for (int mt = 0; mt < 4; ++mt) {
            const int j0 = mt * 16 + quad * 4;
            f32x4 sc, sh;
#pragma unroll
            for (int r = 0; r < 4; ++r) {
                float s = gamma[j0 + r] * rsqrtf(rvar[j0 + r] + 1e-5f);
                sc[r] = s;
                sh[r] = (b1[j0 + r] - rmean[j0 + r]) * s + beta[j0 + r];
            }
            float u0 = fmaxf(c1[mt][0] * sc[0] + sh[0], 0.f);
            float u1 = fmaxf(c1[mt][1] * sc[1] + sh[1], 0.f);
            float u2 = fmaxf(c1[mt][2] * sc[2] + sh[2], 0.f);
            float u3 = fmaxf(c1[mt][3] * sc[3] + sh[3], 0.f);
            uint2 pk;
            pk.x = f2bf(u0) | (f2bf(u1) << 16);
            pk.y = f2bf(u2) | (f2bf(u3) << 16);
            *(uint2*)&Ub[wid][n15][mt * 16 + quad * 4] = pk;
        }
    }
    // W2 frags: issue before the fence, overlap phase-2 tail
    short8 wf2[8];
#pragma unroll
    for (int f = 0; f < 8; ++f) wf2[f] = Wp8[(8 + f) * 64 + lane];
    __threadfence_block();   // same-wave LDS visibility

    // ---- phase 3: GEMM2 + ReLU -> hb_next ----
    {
        short8 u0 = *(const short8*)&Ub[wid][n15][quad * 8];
        short8 u1 = *(const short8*)&Ub[wid][n15][32 + quad * 8];
        f32x4 c2[4];
#pragma unroll
        for (int tc = 0; tc < 4; ++tc) {
            c2[tc] = (f32x4){0.f, 0.f, 0.f, 0.f};
            c2[tc] = __builtin_amdgcn_mfma_f32_16x16x32_bf16(u0, wf2[tc * 2 + 0], c2[tc], 0, 0, 0);
            c2[tc] = __builtin_amdgcn_mfma_f32_16x16x32_bf16(u1, wf2[tc * 2 + 1], c2[tc], 0, 0, 0);
        }
#pragma unroll
        for (int tc = 0; tc < 4; ++tc) {
            const float bb2 = b2[tc * 16 + n15];
#pragma unroll
            for (int r = 0; r < 4; ++r) {
                float v = fmaxf(c2[tc][r] + bb2, 0.f);
                hbn[(size_t)(nb + quad * 4 + r) * 64 + tc * 16 + n15] = (ushort)f2bf(v);
            }
        }
    }
}

// ---------------- global_add_pool (batch sorted -> run-length + atomics) --------

__global__ void pool_kernel(const ushort* __restrict__ hb, const int* __restrict__ batch,
                            float* __restrict__ pooled, int n) {
    const int lane = threadIdx.x & 63;
    const int wid  = threadIdx.x >> 6;
    const int wave = blockIdx.x * 4 + wid;
    const int nwaves = gridDim.x * 4;
    const int per = (n + nwaves - 1) / nwaves;
    const int a = wave * per;
    const int b = min(a + per, n);
    if (a >= b) return;
    int cur = batch[a];
    float sum = 0.0f;
    for (int i = a; i < b; ++i) {
        int g = batch[i];
        if (g != cur) {
            atomicAdd(&pooled[cur * DIM + lane], sum);
            sum = 0.0f;
            cur = g;
        }
        sum += __uint_as_float(((uint)hb[(size_t)i * DIM + lane]) << 16);
    }
    atomicAdd(&pooled[cur * DIM + lane], sum);
}

// ---------------- head: relu(pooled@lin1+b1) @ lin2 + b2 ----------------

__global__ void head_kernel(const float* __restrict__ pooled,
                            const float* __restrict__ w1, const float* __restrict__ b1,
                            const float* __restrict__ w2, const float* __restrict__ b2,
                            float* __restrict__ out) {
    const int g = blockIdx.x;
    const int lane = threadIdx.x;  // 64 threads = 1 wave
    __shared__ float pl[DIM];
    __shared__ float y1l[DIM];
    pl[lane] = pooled[g * DIM + lane];
    __syncthreads();
    float y = b1[lane];
#pragma unroll
    for (int d = 0; d < DIM; ++d) y += pl[d] * w1[d * DIM + lane];
    y1l[lane] = fmaxf(y, 0.0f);
    __syncthreads();
    if (lane < OUT_DIM) {
        float y2 = b2[lane];
#pragma unroll
        for (int d = 0; d < DIM; ++d) y2 += y1l[d] * w2[d * OUT_DIM + lane];
        out[g * OUT_DIM + lane] = y2;
    }
}

// ---------------- launch ----------------

extern "C" void kernel_launch(void* const* d_in, const int* in_sizes, int n_in,
                              void* d_out, int out_size, void* d_ws, size_t ws_size,
                              hipStream_t stream) {
    const float* x     = (const float*)d_in[0];
    const int*   eidx  = (const int*)  d_in[1];   // [2, N_EDGES]: src row then dst row
    const int*   batch = (const int*)  d_in[2];
    const float* W1    = (const float*)d_in[3];
    const float* b1    = (const float*)d_in[4];
    const float* gamma = (const float*)d_in[5];
    const float* beta  = (const float*)d_in[6];
    const float* rmean = (const float*)d_in[7];
    const float* rvar  = (const float*)d_in[8];
    const float* W2    = (const float*)d_in[9];
    const float* b2    = (const float*)d_in[10];
    const float* l1w   = (const float*)d_in[11];
    const float* l1b   = (const float*)d_in[12];
    const float* l2w   = (const float*)d_in[13];
    const float* l2b   = (const float*)d_in[14];
    float* out = (float*)d_out;

    // workspace layout (int-element offsets; 16B alignment preserved)
    const size_t C8 = (size_t)N_CHUNKS * N_RANGES * RANGE_SIZE;   // 3,670,016
    const size_t B8 = (size_t)N_CHUNKS * NODE_PAD;                // 3,670,016
    const size_t ROWS = (size_t)N_NODES + 1;      // +1 zero row for masked gather pad
    int* counts8   = (int*)d_ws;
    int* row_ptr   = counts8   + C8;              // 100352
    int* blockSums = row_ptr   + 100352;          // 256
    int* blockOffs = blockSums + 256;             // 256
    int* base8     = blockOffs + 256;             // B8
    int* col_idx   = base8     + B8;              // 1600000
    uint4* Wp      = (uint4*)(col_idx + 1600000); // 5120 uint4 = 80KB
    ushort* tb     = (ushort*)(Wp + 5120);        // (100000+1)*64 bf16  [ping]
    ushort* hb     = tb + ROWS * DIM;             // (100000+1)*64 bf16  [pong]
    float* pooled  = (float*)(hb + ROWS * DIM);   // 128*64 fp32

    const int* srcp = eidx;
    const int* dstp = eidx + N_EDGES;

    hipMemsetAsync(pooled, 0, N_GRAPHS * DIM * sizeof(float), stream);
    // zero pad row (index N_NODES) in BOTH ping-pong buffers; never written after
    hipMemsetAsync(tb + (size_t)N_NODES * DIM, 0, DIM * sizeof(ushort), stream);
    hipMemsetAsync(hb + (size_t)N_NODES * DIM, 0, DIM * sizeof(ushort), stream);

    cvt_kernel<<<(N_NODES * DIM / 4 + 255) / 256, 256, 0, stream>>>(x, hb, N_NODES * DIM / 4);
    repack_kernel<<<1, 640, 0, stream>>>(W1, W2, Wp);
    histo_kernel<<<N_CHUNKS * 8, 1024, 0, stream>>>(dstp, counts8);
    scanA_kernel<<<SCAN_NB, 256, 0, stream>>>(counts8, blockSums, N_NODES);
    scanB_kernel<<<1, 256, 0, stream>>>(blockSums, blockOffs, row_ptr);
    scanC_kernel<<<SCAN_NB, 256, 0, stream>>>(counts8, blockOffs, row_ptr, base8, N_NODES);
    fill_kernel<<<N_CHUNKS * 8, 1024, 0, stream>>>(srcp, dstp, base8, col_idx);

    const int ntiles = N_NODES / 16;             // 6250 16-node tiles (R7 config)
    const int layer_blocks = (ntiles + 3) / 4;   // 1563: one tile per wave
    ushort* cur = hb;
    ushort* nxt = tb;
    for (int l = 0; l < 5; ++l) {
        layer_kernel<<<layer_blocks, 256, 0, stream>>>(
            cur, nxt, row_ptr, col_idx, Wp + (size_t)l * 2 * 8 * 64,
            b1 + (size_t)l * DIM, gamma + (size_t)l * DIM, beta + (size_t)l * DIM,
            rmean + (size_t)l * DIM, rvar + (size_t)l * DIM, b2 + (size_t)l * DIM, ntiles);
        ushort* t = cur; cur = nxt; nxt = t;
    }
    pool_kernel<<<2048, 256, 0, stream>>>(cur, batch, pooled, N_NODES);
    head_kernel<<<N_GRAPHS, 64, 0, stream>>>(pooled, l1w, l1b, l2w, l2b, out);
}